// Round 1
// 625.441 us; speedup vs baseline: 1.0288x; 1.0288x over previous
//
#include <hip/hip_runtime.h>
#include <stdint.h>

#define N_TOK 65536
#define CDIM  512
#define C3    1536
#define HEADS 8
#define DHEAD 64
#define KTOK  256
#define PGRP  256

typedef __attribute__((ext_vector_type(8))) short bf16x8;
typedef __attribute__((ext_vector_type(4))) float f32x4;

__device__ __forceinline__ unsigned short f2bf(float f) {
  union { float f; unsigned u; } t; t.f = f;
  return (unsigned short)((t.u + 0x7fffu + ((t.u >> 16) & 1u)) >> 16);
}

// ------------- elementwise f32 -> bf16 (vectorized) ------------------------
__global__ __launch_bounds__(256) void cvt_f32_bf16(const float* __restrict__ in,
                                                    unsigned short* __restrict__ out) {
  size_t i = ((size_t)blockIdx.x * 256 + threadIdx.x) * 4;
  float4 v = *(const float4*)(in + i);
  ushort4 o;
  o.x = f2bf(v.x); o.y = f2bf(v.y); o.z = f2bf(v.z); o.w = f2bf(v.w);
  *(ushort4*)(out + i) = o;
}

// ------------- transpose + convert (f32 R x Cc -> bf16 Cc x R) -------------
__global__ __launch_bounds__(256) void transpose_cvt(const float* __restrict__ in,
                                                     unsigned short* __restrict__ out,
                                                     int R, int Cc) {
  __shared__ float tile[32][33];
  int c0 = blockIdx.x * 32, r0 = blockIdx.y * 32;
  int tx = threadIdx.x & 31, ty = threadIdx.x >> 5;  // 32 x 8
  for (int i = ty; i < 32; i += 8)
    tile[i][tx] = in[(size_t)(r0 + i) * Cc + c0 + tx];
  __syncthreads();
  for (int i = ty; i < 32; i += 8)
    out[(size_t)(c0 + i) * R + r0 + tx] = f2bf(tile[tx][i]);
}

// ---------------- GEMM: C[m,n] = A[gather(m),:] @ Bt[n,:]^T + bias[n] ------
// A, Bt bf16; bias f32; output bf16 (OF32=0) or f32 (OF32=1).
// 128x128 tile, BK=64, 256 threads (4 waves 2x2), 16x16x32 bf16 MFMA,
// global_load_lds 16B/lane, 16B-group XOR swizzle on LDS.
// XCD-aware bijective block swizzle (T1): the nbn column-blocks sharing one
// bm-group (same 128 gathered A rows) are consecutive work ids; map each
// XCD (= blockIdx.x % 8 under round-robin dispatch) to a CONTIGUOUS chunk of
// work ids so those blocks share one L2 and are co-resident in time.
// Requires gridDim.x % 8 == 0 (6144 and 2048 here).
template <int OF32>
__global__ __launch_bounds__(256) void gemm_bt(const unsigned short* __restrict__ A,
                                               const unsigned short* __restrict__ Bt,
                                               const float* __restrict__ bias,
                                               void* __restrict__ Cout,
                                               const int* __restrict__ gather,
                                               int Nn, int Kk, int nbn) {
  __shared__ __align__(16) unsigned short As[128 * 64];
  __shared__ __align__(16) unsigned short Bs[128 * 64];
  int cpx = gridDim.x >> 3;                       // chunks per XCD
  int wk = (blockIdx.x & 7) * cpx + (blockIdx.x >> 3);  // bijective XCD swizzle
  int bm = wk / nbn, bn = wk % nbn;
  int m0 = bm * 128, n0 = bn * 128;
  int tid = threadIdx.x;
  int wv = tid >> 6, ln = tid & 63, g = ln >> 4, c = ln & 15;
  int wr = wv >> 1, wc = wv & 1;

  const unsigned short* aptr[4];
  const unsigned short* bptr[4];
#pragma unroll
  for (int i = 0; i < 4; ++i) {
    int s = wv * 256 + i * 64 + ln;   // slot 0..1023, 16B each
    int r = s >> 3, pp = s & 7;
    int cg = pp ^ (r & 7);            // which 8-col group this slot holds
    int ga = gather ? gather[m0 + r] : (m0 + r);
    aptr[i] = A + (size_t)ga * Kk + cg * 8;
    bptr[i] = Bt + (size_t)(n0 + r) * Kk + cg * 8;
  }

  f32x4 acc[4][4];
#pragma unroll
  for (int mi = 0; mi < 4; ++mi)
#pragma unroll
    for (int ni = 0; ni < 4; ++ni)
      acc[mi][ni] = (f32x4){0.f, 0.f, 0.f, 0.f};

  for (int k0 = 0; k0 < Kk; k0 += 64) {
    __syncthreads();
#pragma unroll
    for (int i = 0; i < 4; ++i) {
      __builtin_amdgcn_global_load_lds(
          (__attribute__((address_space(1))) void*)(void*)(aptr[i] + k0),
          (__attribute__((address_space(3))) void*)&As[(wv * 256 + i * 64) * 8],
          16, 0, 0);
      __builtin_amdgcn_global_load_lds(
          (__attribute__((address_space(1))) void*)(void*)(bptr[i] + k0),
          (__attribute__((address_space(3))) void*)&Bs[(wv * 256 + i * 64) * 8],
          16, 0, 0);
    }
    __syncthreads();
#pragma unroll
    for (int kc = 0; kc < 2; ++kc) {
      bf16x8 af[4], bfv[4];
#pragma unroll
      for (int mi = 0; mi < 4; ++mi) {
        int m = wr * 64 + mi * 16 + c;
        af[mi] = *(const bf16x8*)&As[(m * 8 + ((kc * 4 + g) ^ (m & 7))) * 8];
      }
#pragma unroll
      for (int ni = 0; ni < 4; ++ni) {
        int n = wc * 64 + ni * 16 + c;
        bfv[ni] = *(const bf16x8*)&Bs[(n * 8 + ((kc * 4 + g) ^ (n & 7))) * 8];
      }
#pragma unroll
      for (int mi = 0; mi < 4; ++mi)
#pragma unroll
        for (int ni = 0; ni < 4; ++ni)
          acc[mi][ni] = __builtin_amdgcn_mfma_f32_16x16x32_bf16(af[mi], bfv[ni], acc[mi][ni], 0, 0, 0);
    }
  }

#pragma unroll
  for (int ni = 0; ni < 4; ++ni) {
    int col = n0 + wc * 64 + ni * 16 + c;
    float bv = bias[col];
#pragma unroll
    for (int mi = 0; mi < 4; ++mi)
#pragma unroll
      for (int rr = 0; rr < 4; ++rr) {
        int row = m0 + wr * 64 + mi * 16 + g * 4 + rr;
        float v = acc[mi][ni][rr] + bv;
        if (OF32)
          ((float*)Cout)[(size_t)row * Nn + col] = v;
        else
          ((unsigned short*)Cout)[(size_t)row * Nn + col] = f2bf(v);
      }
  }
}

// ---------------- attention: one workgroup per (p, h) ----------------------
// qkv (bf16) is the permuted (N, 1536) buffer; q at col h*64, k at 512+h*64,
// v at 1024+h*64. Output scattered to row order[n] (bf16) so the proj GEMM
// reads contiguously.
// LDS = Ks 32K + Vt 32K + Pt 16K = 80 KB -> 2 blocks/CU (8 waves).
// Pt is per-wave, chunked (16x64) and double-buffered: wave-internal LDS
// ordering via lgkmcnt, NO barriers needed in the t-loop.
__global__ __launch_bounds__(256, 2) void attn_k(const unsigned short* __restrict__ qkv,
                                                 const int* __restrict__ order,
                                                 unsigned short* __restrict__ attnout) {
  __shared__ __align__(16) unsigned short Ks[KTOK * 64];       // [m][d], XOR-swizzled 16B groups
  __shared__ __align__(16) unsigned short Vt[64 * 256];        // [d][m] transposed, XOR-swizzled
  __shared__ __align__(16) unsigned short Pt[4][2][16 * 64];   // per-wave, double-buffered chunk

  int p = blockIdx.x >> 3, h = blockIdx.x & 7;
  int tid = threadIdx.x;
  int wv = tid >> 6, ln = tid & 63, g = ln >> 4, c = ln & 15;

  const unsigned short* base = qkv + (size_t)p * KTOK * C3 + h * DHEAD;

  // stage K rows and V transposed
  {
    const unsigned short* krow = base + CDIM + (size_t)tid * C3;
#pragma unroll
    for (int j = 0; j < 8; ++j) {
      bf16x8 kv = *(const bf16x8*)(krow + j * 8);
      *(bf16x8*)&Ks[(tid * 8 + (j ^ (tid & 7))) * 8] = kv;
    }
    const unsigned short* vrow = base + 2 * CDIM + (size_t)tid * C3;
#pragma unroll
    for (int j = 0; j < 8; ++j) {
      bf16x8 vvv = *(const bf16x8*)(vrow + j * 8);
#pragma unroll
      for (int e = 0; e < 8; ++e) {
        int d = j * 8 + e;
        Vt[d * 256 + (((tid >> 3) ^ (d & 7)) << 3) + (tid & 7)] = (unsigned short)vvv[e];
      }
    }
  }
  __syncthreads();

#pragma unroll 1
  for (int t = 0; t < 4; ++t) {
    int q0 = wv * 64 + t * 16;
    const unsigned short* qrow = base + (size_t)(q0 + c) * C3;
    bf16x8 aq0 = *(const bf16x8*)(qrow + g * 8);
    bf16x8 aq1 = *(const bf16x8*)(qrow + 32 + g * 8);

    // S = Q K^T  (16 q-rows x 256 m-cols), C/D: row=g*4+reg (q), col=c
    f32x4 s[16];
#pragma unroll
    for (int mt = 0; mt < 16; ++mt) {
      int m = mt * 16 + c;
      bf16x8 bk0 = *(const bf16x8*)&Ks[(m * 8 + ((0 + g) ^ (m & 7))) * 8];
      bf16x8 bk1 = *(const bf16x8*)&Ks[(m * 8 + ((4 + g) ^ (m & 7))) * 8];
      f32x4 z = (f32x4){0.f, 0.f, 0.f, 0.f};
      z = __builtin_amdgcn_mfma_f32_16x16x32_bf16(aq0, bk0, z, 0, 0, 0);
      s[mt] = __builtin_amdgcn_mfma_f32_16x16x32_bf16(aq1, bk1, z, 0, 0, 0);
    }

    // softmax over m: 16 mt tiles in-reg + 16 lanes (shfl_xor 1..8, same g)
    float mx[4], sm[4];
#pragma unroll
    for (int rr = 0; rr < 4; ++rr) {
      float m1 = s[0][rr];
#pragma unroll
      for (int mt = 1; mt < 16; ++mt) m1 = fmaxf(m1, s[mt][rr]);
#pragma unroll
      for (int off = 1; off < 16; off <<= 1) m1 = fmaxf(m1, __shfl_xor(m1, off, 64));
      mx[rr] = m1;
    }
#pragma unroll
    for (int rr = 0; rr < 4; ++rr) sm[rr] = 0.f;
#pragma unroll
    for (int mt = 0; mt < 16; ++mt)
#pragma unroll
      for (int rr = 0; rr < 4; ++rr) {
        float e = __expf((s[mt][rr] - mx[rr]) * 0.125f);
        s[mt][rr] = e;
        sm[rr] += e;
      }
#pragma unroll
    for (int rr = 0; rr < 4; ++rr) {
      float t2 = sm[rr];
#pragma unroll
      for (int off = 1; off < 16; off <<= 1) t2 += __shfl_xor(t2, off, 64);
      sm[rr] = 1.f / t2;
    }

    // O = P V, chunked: write 16x64 P-chunk (A-layout) to per-wave LDS,
    // read its two A-frags, MFMA; double-buffer chunk parity for WAR.
    f32x4 o[4];
#pragma unroll
    for (int dt = 0; dt < 4; ++dt) o[dt] = (f32x4){0.f, 0.f, 0.f, 0.f};
#pragma unroll
    for (int ch = 0; ch < 4; ++ch) {
      unsigned short* pt = &Pt[wv][ch & 1][0];
#pragma unroll
      for (int mtl = 0; mtl < 4; ++mtl) {
        int mt = ch * 4 + mtl;
        int mcol = mtl * 16 + c;   // 0..63 within chunk
#pragma unroll
        for (int rr = 0; rr < 4; ++rr) {
          int q = g * 4 + rr;
          pt[q * 64 + (((mcol >> 3) ^ (q & 7)) << 3) + (mcol & 7)] =
              f2bf(s[mt][rr] * sm[rr]);
        }
      }
#pragma unroll
      for (int mcl = 0; mcl < 2; ++mcl) {
        int cg = mcl * 4 + g;              // 8-col group within chunk
        bf16x8 ap = *(const bf16x8*)&pt[(c * 8 + (cg ^ (c & 7))) * 8];
        int cgm = (ch * 2 + mcl) * 4 + g;  // global 8-col group within 256
#pragma unroll
        for (int dt = 0; dt < 4; ++dt) {
          int d = dt * 16 + c;
          bf16x8 bv = *(const bf16x8*)&Vt[(d * 32 + (cgm ^ (d & 7))) * 8];
          o[dt] = __builtin_amdgcn_mfma_f32_16x16x32_bf16(ap, bv, o[dt], 0, 0, 0);
        }
      }
    }

    // scatter-store: row order[p*256 + q], col h*64 + d
#pragma unroll
    for (int rr = 0; rr < 4; ++rr) {
      int orow = order[p * KTOK + q0 + g * 4 + rr];
      size_t rb = (size_t)orow * CDIM + h * DHEAD;
#pragma unroll
      for (int dt = 0; dt < 4; ++dt)
        attnout[rb + dt * 16 + c] = f2bf(o[dt][rr]);
    }
  }
}

extern "C" void kernel_launch(void* const* d_in, const int* in_sizes, int n_in,
                              void* d_out, int out_size, void* d_ws, size_t ws_size,
                              hipStream_t stream) {
  const float* feat  = (const float*)d_in[0];
  const int*   order = (const int*)d_in[1];
  // d_in[2] = inverse (unused: we scatter by order instead)
  const float* Wqkv  = (const float*)d_in[3];
  const float* bqkv  = (const float*)d_in[4];
  const float* Wproj = (const float*)d_in[5];
  const float* bproj = (const float*)d_in[6];
  float* out = (float*)d_out;

  // ws layout (bf16 intermediates):
  //   qkv    : N*1536            = 201.3 MB
  //   featb  : N*512             =  67.1 MB  (dead after gemm1; aliased by attn)
  //   wqkvT  : 1536*512          =   1.6 MB
  //   wprojT : 512*512           =   0.5 MB
  char* ws = (char*)d_ws;
  unsigned short* qkv    = (unsigned short*)ws;
  unsigned short* featb  = (unsigned short*)(ws + (size_t)N_TOK * C3 * 2);
  unsigned short* attn   = featb;  // disjoint lifetime
  unsigned short* wqkvT  = (unsigned short*)(ws + (size_t)N_TOK * C3 * 2 + (size_t)N_TOK * CDIM * 2);
  unsigned short* wprojT = wqkvT + C3 * CDIM;

  // f32 -> bf16 conversions
  cvt_f32_bf16<<<(N_TOK * CDIM) / (256 * 4), 256, 0, stream>>>(feat, featb);
  transpose_cvt<<<dim3(C3 / 32, CDIM / 32), 256, 0, stream>>>(Wqkv, wqkvT, CDIM, C3);
  transpose_cvt<<<dim3(CDIM / 32, CDIM / 32), 256, 0, stream>>>(Wproj, wprojT, CDIM, CDIM);

  // qkv[n,:] = feat[order[n],:] @ Wqkv + bqkv   (permuted rows directly)
  gemm_bt<0><<<(N_TOK / 128) * (C3 / 128), 256, 0, stream>>>(
      featb, wqkvT, bqkv, qkv, order, C3, CDIM, C3 / 128);

  // block-local attention, scatter back to original row order
  attn_k<<<PGRP * HEADS, 256, 0, stream>>>(qkv, order, attn);

  // out = attn @ Wproj + bproj  (f32 output)
  gemm_bt<1><<<(N_TOK / 128) * (CDIM / 128), 256, 0, stream>>>(
      attn, wprojT, bproj, out, nullptr, CDIM, CDIM, CDIM / 128);
}

// Round 2
// 576.394 us; speedup vs baseline: 1.1163x; 1.0851x over previous
//
#include <hip/hip_runtime.h>
#include <stdint.h>

#define N_TOK 65536
#define CDIM  512
#define C3    1536
#define HEADS 8
#define DHEAD 64
#define KTOK  256
#define PGRP  256

typedef __attribute__((ext_vector_type(8))) short bf16x8;
typedef __attribute__((ext_vector_type(4))) float f32x4;

__device__ __forceinline__ unsigned short f2bf(float f) {
  union { float f; unsigned u; } t; t.f = f;
  return (unsigned short)((t.u + 0x7fffu + ((t.u >> 16) & 1u)) >> 16);
}

// ------------- elementwise f32 -> bf16 (vectorized) ------------------------
__global__ __launch_bounds__(256) void cvt_f32_bf16(const float* __restrict__ in,
                                                    unsigned short* __restrict__ out) {
  size_t i = ((size_t)blockIdx.x * 256 + threadIdx.x) * 4;
  float4 v = *(const float4*)(in + i);
  ushort4 o;
  o.x = f2bf(v.x); o.y = f2bf(v.y); o.z = f2bf(v.z); o.w = f2bf(v.w);
  *(ushort4*)(out + i) = o;
}

// ------------- transpose + convert (f32 R x Cc -> bf16 Cc x R) -------------
__global__ __launch_bounds__(256) void transpose_cvt(const float* __restrict__ in,
                                                     unsigned short* __restrict__ out,
                                                     int R, int Cc) {
  __shared__ float tile[32][33];
  int c0 = blockIdx.x * 32, r0 = blockIdx.y * 32;
  int tx = threadIdx.x & 31, ty = threadIdx.x >> 5;  // 32 x 8
  for (int i = ty; i < 32; i += 8)
    tile[i][tx] = in[(size_t)(r0 + i) * Cc + c0 + tx];
  __syncthreads();
  for (int i = ty; i < 32; i += 8)
    out[(size_t)(c0 + i) * R + r0 + tx] = f2bf(tile[tx][i]);
}

// ---------------- 256x256 8-phase GEMM (T2+T3+T4+T5 port) ------------------
// C[m,n] = A[gather(m),:] @ Bt[n,:]^T + bias[n].  A, Bt bf16; output bf16/f32.
// BM=BN=256, BK=64, 512 threads = 8 waves (2M x 4N), LDS 128 KiB (2-slot ring).
// Interleaved frag ownership: wave wr owns m-tiles {2*mi+wr}, wave wc owns
// n-tiles {4*ni+wc} -> quadrant (mh,nh) touches exactly one A-half/B-half for
// ALL waves, so halves free up mid-tile and can be restaged 2-ahead.
// Per tile v (4 phases, quadrant order (0,0),(0,1),(1,1),(1,0)):
//   P1: read A(mh0)+B(nh0); stage A-hi(v+1)   [slot^1, fully read last tile]
//   P2: read B(nh1), reuse A; stage B-lo(v+1) [slot^1, read at prev P1/P4]
//   P3: read A(mh1), reuse B; stage A-lo(v+2) [same slot, A-lo only read @P1]
//   P4: read B(nh0);          stage B-hi(v+2) [same slot, B-hi only read @P2]
//   end P4: vmcnt(4) -> everything except the 2 newest half-tiles landed,
//   i.e. tile v+1 is fully in LDS; never drain to 0 in steady state (T4).
// LDS swizzle: 16B-group XOR (slot = row*8 + (cg ^ (row&7))), measured
// conflict-free (SQ_LDS_BANK_CONFLICT=0 on the 128x128 predecessor).
template <int OF32>
__global__ __launch_bounds__(512, 2) void gemm256(const unsigned short* __restrict__ A,
                                                  const unsigned short* __restrict__ Bt,
                                                  const float* __restrict__ bias,
                                                  void* __restrict__ Cout,
                                                  const int* __restrict__ gather,
                                                  int Nn, int Kk, int nbn) {
  __shared__ __align__(16) unsigned short As[2][256 * 64];
  __shared__ __align__(16) unsigned short Bs[2][256 * 64];

  // bijective XCD swizzle (grid % 8 == 0)
  int cpx = gridDim.x >> 3;
  int wk = (blockIdx.x & 7) * cpx + (blockIdx.x >> 3);
  int bm = wk / nbn, bn = wk % nbn;
  int m0 = bm * 256, n0 = bn * 256;

  int tid = threadIdx.x;
  int wv = tid >> 6, ln = tid & 63, g = ln >> 4, c = ln & 15;
  int wr = wv >> 2, wc = wv & 3;     // 2 x 4 wave grid
  int NT = Kk >> 6;                  // 64-wide K-tiles (8 here)

  // staging source byte-offsets: half h2 (128 rows), issue j (64 rows each)
  const char* Ab = (const char*)A;
  const char* Bb = (const char*)Bt;
  int lr = tid >> 3;
  int cg = (tid & 7) ^ (lr & 7);     // pre-swizzled source column-group
  unsigned aoff[2][2], boff[2][2];
#pragma unroll
  for (int h2 = 0; h2 < 2; ++h2)
#pragma unroll
    for (int j = 0; j < 2; ++j) {
      int row = h2 * 128 + j * 64 + lr;
      int ga = gather ? gather[m0 + row] : (m0 + row);
      aoff[h2][j] = (unsigned)(((size_t)ga * Kk + cg * 8) * 2);
      boff[h2][j] = (unsigned)(((size_t)(n0 + row) * Kk + cg * 8) * 2);
    }

#define STAGE_A(t, h2) do { int _s = (t) & 1; unsigned _k = (unsigned)(t) * 128u;             \
    __builtin_amdgcn_global_load_lds(                                                          \
        (__attribute__((address_space(1))) void*)(void*)(Ab + aoff[h2][0] + _k),               \
        (__attribute__((address_space(3))) void*)&As[_s][((h2) * 1024 + wv * 64) * 8],         \
        16, 0, 0);                                                                             \
    __builtin_amdgcn_global_load_lds(                                                          \
        (__attribute__((address_space(1))) void*)(void*)(Ab + aoff[h2][1] + _k),               \
        (__attribute__((address_space(3))) void*)&As[_s][((h2) * 1024 + 512 + wv * 64) * 8],   \
        16, 0, 0);                                                                             \
  } while (0)
#define STAGE_B(t, h2) do { int _s = (t) & 1; unsigned _k = (unsigned)(t) * 128u;             \
    __builtin_amdgcn_global_load_lds(                                                          \
        (__attribute__((address_space(1))) void*)(void*)(Bb + boff[h2][0] + _k),               \
        (__attribute__((address_space(3))) void*)&Bs[_s][((h2) * 1024 + wv * 64) * 8],         \
        16, 0, 0);                                                                             \
    __builtin_amdgcn_global_load_lds(                                                          \
        (__attribute__((address_space(1))) void*)(void*)(Bb + boff[h2][1] + _k),               \
        (__attribute__((address_space(3))) void*)&Bs[_s][((h2) * 1024 + 512 + wv * 64) * 8],   \
        16, 0, 0);                                                                             \
  } while (0)
#define RD_A(mi, kc) (*(const bf16x8*)&Ac[((((2 * (mi) + wr) * 16 + c) * 8 + (((kc) * 4 + g) ^ (c & 7))) * 8)])
#define RD_B(ni, kc) (*(const bf16x8*)&Bc[((((4 * (ni) + wc) * 16 + c) * 8 + (((kc) * 4 + g) ^ (c & 7))) * 8)])

  f32x4 acc[8][4];
#pragma unroll
  for (int mi = 0; mi < 8; ++mi)
#pragma unroll
    for (int ni = 0; ni < 4; ++ni)
      acc[mi][ni] = (f32x4){0.f, 0.f, 0.f, 0.f};

  // prologue: stage tiles 0 and 1 fully; wait tile 0 (tile 1 stays in flight)
  STAGE_A(0, 0); STAGE_A(0, 1); STAGE_B(0, 0); STAGE_B(0, 1);
  STAGE_A(1, 0); STAGE_A(1, 1); STAGE_B(1, 0); STAGE_B(1, 1);
  asm volatile("s_waitcnt vmcnt(8)" ::: "memory");
  __builtin_amdgcn_s_barrier();

  bf16x8 af[4][2], bf[2][2];

#pragma unroll 1
  for (int v = 0; v < NT; ++v) {
    unsigned short* Ac = &As[v & 1][0];
    unsigned short* Bc = &Bs[v & 1][0];

    // ---- P1: quadrant (0,0)
#pragma unroll
    for (int i = 0; i < 4; ++i)
#pragma unroll
      for (int kc = 0; kc < 2; ++kc) af[i][kc] = RD_A(i, kc);
#pragma unroll
    for (int j = 0; j < 2; ++j)
#pragma unroll
      for (int kc = 0; kc < 2; ++kc) bf[j][kc] = RD_B(j, kc);
    if (v >= 1 && v + 1 < NT) STAGE_A(v + 1, 1);
    __builtin_amdgcn_s_barrier();
    asm volatile("s_waitcnt lgkmcnt(0)" ::: "memory");
    __builtin_amdgcn_sched_barrier(0);
    __builtin_amdgcn_s_setprio(1);
#pragma unroll
    for (int i = 0; i < 4; ++i)
#pragma unroll
      for (int j = 0; j < 2; ++j) {
        acc[i][j] = __builtin_amdgcn_mfma_f32_16x16x32_bf16(af[i][0], bf[j][0], acc[i][j], 0, 0, 0);
        acc[i][j] = __builtin_amdgcn_mfma_f32_16x16x32_bf16(af[i][1], bf[j][1], acc[i][j], 0, 0, 0);
      }
    __builtin_amdgcn_s_setprio(0);
    __builtin_amdgcn_s_barrier();

    // ---- P2: quadrant (0,1) — reuse A frags
#pragma unroll
    for (int j = 0; j < 2; ++j)
#pragma unroll
      for (int kc = 0; kc < 2; ++kc) bf[j][kc] = RD_B(2 + j, kc);
    if (v >= 1 && v + 1 < NT) STAGE_B(v + 1, 0);
    __builtin_amdgcn_s_barrier();
    asm volatile("s_waitcnt lgkmcnt(0)" ::: "memory");
    __builtin_amdgcn_sched_barrier(0);
    __builtin_amdgcn_s_setprio(1);
#pragma unroll
    for (int i = 0; i < 4; ++i)
#pragma unroll
      for (int j = 0; j < 2; ++j) {
        acc[i][2 + j] = __builtin_amdgcn_mfma_f32_16x16x32_bf16(af[i][0], bf[j][0], acc[i][2 + j], 0, 0, 0);
        acc[i][2 + j] = __builtin_amdgcn_mfma_f32_16x16x32_bf16(af[i][1], bf[j][1], acc[i][2 + j], 0, 0, 0);
      }
    __builtin_amdgcn_s_setprio(0);
    __builtin_amdgcn_s_barrier();

    // ---- P3: quadrant (1,1) — reuse B frags
#pragma unroll
    for (int i = 0; i < 4; ++i)
#pragma unroll
      for (int kc = 0; kc < 2; ++kc) af[i][kc] = RD_A(4 + i, kc);
    if (v + 2 < NT) STAGE_A(v + 2, 0);
    __builtin_amdgcn_s_barrier();
    asm volatile("s_waitcnt lgkmcnt(0)" ::: "memory");
    __builtin_amdgcn_sched_barrier(0);
    __builtin_amdgcn_s_setprio(1);
#pragma unroll
    for (int i = 0; i < 4; ++i)
#pragma unroll
      for (int j = 0; j < 2; ++j) {
        acc[4 + i][2 + j] = __builtin_amdgcn_mfma_f32_16x16x32_bf16(af[i][0], bf[j][0], acc[4 + i][2 + j], 0, 0, 0);
        acc[4 + i][2 + j] = __builtin_amdgcn_mfma_f32_16x16x32_bf16(af[i][1], bf[j][1], acc[4 + i][2 + j], 0, 0, 0);
      }
    __builtin_amdgcn_s_setprio(0);
    __builtin_amdgcn_s_barrier();

    // ---- P4: quadrant (1,0) — reuse A frags, re-read B(nh0)
#pragma unroll
    for (int j = 0; j < 2; ++j)
#pragma unroll
      for (int kc = 0; kc < 2; ++kc) bf[j][kc] = RD_B(j, kc);
    if (v + 2 < NT) STAGE_B(v + 2, 1);
    __builtin_amdgcn_s_barrier();
    asm volatile("s_waitcnt lgkmcnt(0)" ::: "memory");
    __builtin_amdgcn_sched_barrier(0);
    __builtin_amdgcn_s_setprio(1);
#pragma unroll
    for (int i = 0; i < 4; ++i)
#pragma unroll
      for (int j = 0; j < 2; ++j) {
        acc[4 + i][j] = __builtin_amdgcn_mfma_f32_16x16x32_bf16(af[i][0], bf[j][0], acc[4 + i][j], 0, 0, 0);
        acc[4 + i][j] = __builtin_amdgcn_mfma_f32_16x16x32_bf16(af[i][1], bf[j][1], acc[4 + i][j], 0, 0, 0);
      }
    __builtin_amdgcn_s_setprio(0);
    // counted vmcnt (T4): tile v+1 fully landed; 2 newest half-tiles in flight
    if (v + 2 < NT) asm volatile("s_waitcnt vmcnt(4)" ::: "memory");
    else            asm volatile("s_waitcnt vmcnt(0)" ::: "memory");
    __builtin_amdgcn_s_barrier();
  }

  // epilogue
#pragma unroll
  for (int ni = 0; ni < 4; ++ni) {
    int col = n0 + (4 * ni + wc) * 16 + c;
    float bv = bias[col];
#pragma unroll
    for (int mi = 0; mi < 8; ++mi) {
      int rowb = m0 + (2 * mi + wr) * 16 + g * 4;
#pragma unroll
      for (int rr = 0; rr < 4; ++rr) {
        float vv = acc[mi][ni][rr] + bv;
        if (OF32) ((float*)Cout)[(size_t)(rowb + rr) * Nn + col] = vv;
        else ((unsigned short*)Cout)[(size_t)(rowb + rr) * Nn + col] = f2bf(vv);
      }
    }
  }
#undef STAGE_A
#undef STAGE_B
#undef RD_A
#undef RD_B
}

// ---------------- attention: one workgroup per (p, h) ----------------------
// qkv (bf16) is the permuted (N, 1536) buffer; q at col h*64, k at 512+h*64,
// v at 1024+h*64. Output scattered to row order[n] (bf16) so the proj GEMM
// reads contiguously.
// LDS = Ks 32K + Vt 32K + Pt 16K = 80 KB -> 2 blocks/CU (8 waves).
// Pt is per-wave, chunked (16x64) and double-buffered: wave-internal LDS
// ordering via lgkmcnt, NO barriers needed in the t-loop.
__global__ __launch_bounds__(256, 2) void attn_k(const unsigned short* __restrict__ qkv,
                                                 const int* __restrict__ order,
                                                 unsigned short* __restrict__ attnout) {
  __shared__ __align__(16) unsigned short Ks[KTOK * 64];       // [m][d], XOR-swizzled 16B groups
  __shared__ __align__(16) unsigned short Vt[64 * 256];        // [d][m] transposed, XOR-swizzled
  __shared__ __align__(16) unsigned short Pt[4][2][16 * 64];   // per-wave, double-buffered chunk

  int p = blockIdx.x >> 3, h = blockIdx.x & 7;
  int tid = threadIdx.x;
  int wv = tid >> 6, ln = tid & 63, g = ln >> 4, c = ln & 15;

  const unsigned short* base = qkv + (size_t)p * KTOK * C3 + h * DHEAD;

  // stage K rows and V transposed
  {
    const unsigned short* krow = base + CDIM + (size_t)tid * C3;
#pragma unroll
    for (int j = 0; j < 8; ++j) {
      bf16x8 kv = *(const bf16x8*)(krow + j * 8);
      *(bf16x8*)&Ks[(tid * 8 + (j ^ (tid & 7))) * 8] = kv;
    }
    const unsigned short* vrow = base + 2 * CDIM + (size_t)tid * C3;
#pragma unroll
    for (int j = 0; j < 8; ++j) {
      bf16x8 vvv = *(const bf16x8*)(vrow + j * 8);
#pragma unroll
      for (int e = 0; e < 8; ++e) {
        int d = j * 8 + e;
        Vt[d * 256 + (((tid >> 3) ^ (d & 7)) << 3) + (tid & 7)] = (unsigned short)vvv[e];
      }
    }
  }
  __syncthreads();

#pragma unroll 1
  for (int t = 0; t < 4; ++t) {
    int q0 = wv * 64 + t * 16;
    const unsigned short* qrow = base + (size_t)(q0 + c) * C3;
    bf16x8 aq0 = *(const bf16x8*)(qrow + g * 8);
    bf16x8 aq1 = *(const bf16x8*)(qrow + 32 + g * 8);

    // S = Q K^T  (16 q-rows x 256 m-cols), C/D: row=g*4+reg (q), col=c
    f32x4 s[16];
#pragma unroll
    for (int mt = 0; mt < 16; ++mt) {
      int m = mt * 16 + c;
      bf16x8 bk0 = *(const bf16x8*)&Ks[(m * 8 + ((0 + g) ^ (m & 7))) * 8];
      bf16x8 bk1 = *(const bf16x8*)&Ks[(m * 8 + ((4 + g) ^ (m & 7))) * 8];
      f32x4 z = (f32x4){0.f, 0.f, 0.f, 0.f};
      z = __builtin_amdgcn_mfma_f32_16x16x32_bf16(aq0, bk0, z, 0, 0, 0);
      s[mt] = __builtin_amdgcn_mfma_f32_16x16x32_bf16(aq1, bk1, z, 0, 0, 0);
    }

    // softmax over m: 16 mt tiles in-reg + 16 lanes (shfl_xor 1..8, same g)
    float mx[4], sm[4];
#pragma unroll
    for (int rr = 0; rr < 4; ++rr) {
      float m1 = s[0][rr];
#pragma unroll
      for (int mt = 1; mt < 16; ++mt) m1 = fmaxf(m1, s[mt][rr]);
#pragma unroll
      for (int off = 1; off < 16; off <<= 1) m1 = fmaxf(m1, __shfl_xor(m1, off, 64));
      mx[rr] = m1;
    }
#pragma unroll
    for (int rr = 0; rr < 4; ++rr) sm[rr] = 0.f;
#pragma unroll
    for (int mt = 0; mt < 16; ++mt)
#pragma unroll
      for (int rr = 0; rr < 4; ++rr) {
        float e = __expf((s[mt][rr] - mx[rr]) * 0.125f);
        s[mt][rr] = e;
        sm[rr] += e;
      }
#pragma unroll
    for (int rr = 0; rr < 4; ++rr) {
      float t2 = sm[rr];
#pragma unroll
      for (int off = 1; off < 16; off <<= 1) t2 += __shfl_xor(t2, off, 64);
      sm[rr] = 1.f / t2;
    }

    // O = P V, chunked: write 16x64 P-chunk (A-layout) to per-wave LDS,
    // read its two A-frags, MFMA; double-buffer chunk parity for WAR.
    f32x4 o[4];
#pragma unroll
    for (int dt = 0; dt < 4; ++dt) o[dt] = (f32x4){0.f, 0.f, 0.f, 0.f};
#pragma unroll
    for (int ch = 0; ch < 4; ++ch) {
      unsigned short* pt = &Pt[wv][ch & 1][0];
#pragma unroll
      for (int mtl = 0; mtl < 4; ++mtl) {
        int mt = ch * 4 + mtl;
        int mcol = mtl * 16 + c;   // 0..63 within chunk
#pragma unroll
        for (int rr = 0; rr < 4; ++rr) {
          int q = g * 4 + rr;
          pt[q * 64 + (((mcol >> 3) ^ (q & 7)) << 3) + (mcol & 7)] =
              f2bf(s[mt][rr] * sm[rr]);
        }
      }
#pragma unroll
      for (int mcl = 0; mcl < 2; ++mcl) {
        int cg = mcl * 4 + g;              // 8-col group within chunk
        bf16x8 ap = *(const bf16x8*)&pt[(c * 8 + (cg ^ (c & 7))) * 8];
        int cgm = (ch * 2 + mcl) * 4 + g;  // global 8-col group within 256
#pragma unroll
        for (int dt = 0; dt < 4; ++dt) {
          int d = dt * 16 + c;
          bf16x8 bv = *(const bf16x8*)&Vt[(d * 32 + (cgm ^ (d & 7))) * 8];
          o[dt] = __builtin_amdgcn_mfma_f32_16x16x32_bf16(ap, bv, o[dt], 0, 0, 0);
        }
      }
    }

    // scatter-store: row order[p*256 + q], col h*64 + d
#pragma unroll
    for (int rr = 0; rr < 4; ++rr) {
      int orow = order[p * KTOK + q0 + g * 4 + rr];
      size_t rb = (size_t)orow * CDIM + h * DHEAD;
#pragma unroll
      for (int dt = 0; dt < 4; ++dt)
        attnout[rb + dt * 16 + c] = f2bf(o[dt][rr]);
    }
  }
}

extern "C" void kernel_launch(void* const* d_in, const int* in_sizes, int n_in,
                              void* d_out, int out_size, void* d_ws, size_t ws_size,
                              hipStream_t stream) {
  const float* feat  = (const float*)d_in[0];
  const int*   order = (const int*)d_in[1];
  // d_in[2] = inverse (unused: we scatter by order instead)
  const float* Wqkv  = (const float*)d_in[3];
  const float* bqkv  = (const float*)d_in[4];
  const float* Wproj = (const float*)d_in[5];
  const float* bproj = (const float*)d_in[6];
  float* out = (float*)d_out;

  // ws layout (bf16 intermediates):
  //   qkv    : N*1536            = 201.3 MB
  //   featb  : N*512             =  67.1 MB  (dead after gemm1; aliased by attn)
  //   wqkvT  : 1536*512          =   1.6 MB
  //   wprojT : 512*512           =   0.5 MB
  char* ws = (char*)d_ws;
  unsigned short* qkv    = (unsigned short*)ws;
  unsigned short* featb  = (unsigned short*)(ws + (size_t)N_TOK * C3 * 2);
  unsigned short* attn   = featb;  // disjoint lifetime
  unsigned short* wqkvT  = (unsigned short*)(ws + (size_t)N_TOK * C3 * 2 + (size_t)N_TOK * CDIM * 2);
  unsigned short* wprojT = wqkvT + C3 * CDIM;

  // f32 -> bf16 conversions
  cvt_f32_bf16<<<(N_TOK * CDIM) / (256 * 4), 256, 0, stream>>>(feat, featb);
  transpose_cvt<<<dim3(C3 / 32, CDIM / 32), 256, 0, stream>>>(Wqkv, wqkvT, CDIM, C3);
  transpose_cvt<<<dim3(CDIM / 32, CDIM / 32), 256, 0, stream>>>(Wproj, wprojT, CDIM, CDIM);

  // qkv[n,:] = feat[order[n],:] @ Wqkv + bqkv   (permuted rows directly)
  gemm256<0><<<(N_TOK / 256) * (C3 / 256), 512, 0, stream>>>(
      featb, wqkvT, bqkv, qkv, order, C3, CDIM, C3 / 256);

  // block-local attention, scatter back to original row order
  attn_k<<<PGRP * HEADS, 256, 0, stream>>>(qkv, order, attn);

  // out = attn @ Wproj + bproj  (f32 output)
  gemm256<1><<<(N_TOK / 256) * (CDIM / 256), 512, 0, stream>>>(
      attn, wprojT, bproj, out, nullptr, CDIM, CDIM, CDIM / 256);
}

// Round 3
// 496.668 us; speedup vs baseline: 1.2955x; 1.1605x over previous
//
#include <hip/hip_runtime.h>
#include <stdint.h>

#define N_TOK 65536
#define CDIM  512
#define C3    1536
#define HEADS 8
#define DHEAD 64
#define KTOK  256
#define PGRP  256

typedef __attribute__((ext_vector_type(8))) short bf16x8;
typedef __attribute__((ext_vector_type(4))) float f32x4;
typedef __attribute__((ext_vector_type(16))) float f32x16;
typedef __attribute__((ext_vector_type(4))) unsigned u32x4;

__device__ __forceinline__ unsigned short f2bf(float f) {
  union { float f; unsigned u; } t; t.f = f;
  return (unsigned short)((t.u + 0x7fffu + ((t.u >> 16) & 1u)) >> 16);
}

__device__ __forceinline__ unsigned cvt_pk_bf16(float lo, float hi) {
  unsigned r;
  asm("v_cvt_pk_bf16_f32 %0, %1, %2" : "=v"(r) : "v"(lo), "v"(hi));
  return r;
}

// ------------- elementwise f32 -> bf16 (vectorized) ------------------------
__global__ __launch_bounds__(256) void cvt_f32_bf16(const float* __restrict__ in,
                                                    unsigned short* __restrict__ out) {
  size_t i = ((size_t)blockIdx.x * 256 + threadIdx.x) * 4;
  float4 v = *(const float4*)(in + i);
  ushort4 o;
  o.x = f2bf(v.x); o.y = f2bf(v.y); o.z = f2bf(v.z); o.w = f2bf(v.w);
  *(ushort4*)(out + i) = o;
}

// ------------- transpose + convert (f32 R x Cc -> bf16 Cc x R) -------------
__global__ __launch_bounds__(256) void transpose_cvt(const float* __restrict__ in,
                                                     unsigned short* __restrict__ out,
                                                     int R, int Cc) {
  __shared__ float tile[32][33];
  int c0 = blockIdx.x * 32, r0 = blockIdx.y * 32;
  int tx = threadIdx.x & 31, ty = threadIdx.x >> 5;  // 32 x 8
  for (int i = ty; i < 32; i += 8)
    tile[i][tx] = in[(size_t)(r0 + i) * Cc + c0 + tx];
  __syncthreads();
  for (int i = ty; i < 32; i += 8)
    out[(size_t)(c0 + i) * R + r0 + tx] = f2bf(tile[tx][i]);
}

// ---------------- 256x256 8-phase GEMM (T2+T3+T4+T5 port) ------------------
// (unchanged from previous round — see comments there)
template <int OF32>
__global__ __launch_bounds__(512, 2) void gemm256(const unsigned short* __restrict__ A,
                                                  const unsigned short* __restrict__ Bt,
                                                  const float* __restrict__ bias,
                                                  void* __restrict__ Cout,
                                                  const int* __restrict__ gather,
                                                  int Nn, int Kk, int nbn) {
  __shared__ __align__(16) unsigned short As[2][256 * 64];
  __shared__ __align__(16) unsigned short Bs[2][256 * 64];

  int cpx = gridDim.x >> 3;
  int wk = (blockIdx.x & 7) * cpx + (blockIdx.x >> 3);
  int bm = wk / nbn, bn = wk % nbn;
  int m0 = bm * 256, n0 = bn * 256;

  int tid = threadIdx.x;
  int wv = tid >> 6, ln = tid & 63, g = ln >> 4, c = ln & 15;
  int wr = wv >> 2, wc = wv & 3;
  int NT = Kk >> 6;

  const char* Ab = (const char*)A;
  const char* Bb = (const char*)Bt;
  int lr = tid >> 3;
  int cg = (tid & 7) ^ (lr & 7);
  unsigned aoff[2][2], boff[2][2];
#pragma unroll
  for (int h2 = 0; h2 < 2; ++h2)
#pragma unroll
    for (int j = 0; j < 2; ++j) {
      int row = h2 * 128 + j * 64 + lr;
      int ga = gather ? gather[m0 + row] : (m0 + row);
      aoff[h2][j] = (unsigned)(((size_t)ga * Kk + cg * 8) * 2);
      boff[h2][j] = (unsigned)(((size_t)(n0 + row) * Kk + cg * 8) * 2);
    }

#define STAGE_A(t, h2) do { int _s = (t) & 1; unsigned _k = (unsigned)(t) * 128u;             \
    __builtin_amdgcn_global_load_lds(                                                          \
        (__attribute__((address_space(1))) void*)(void*)(Ab + aoff[h2][0] + _k),               \
        (__attribute__((address_space(3))) void*)&As[_s][((h2) * 1024 + wv * 64) * 8],         \
        16, 0, 0);                                                                             \
    __builtin_amdgcn_global_load_lds(                                                          \
        (__attribute__((address_space(1))) void*)(void*)(Ab + aoff[h2][1] + _k),               \
        (__attribute__((address_space(3))) void*)&As[_s][((h2) * 1024 + 512 + wv * 64) * 8],   \
        16, 0, 0);                                                                             \
  } while (0)
#define STAGE_B(t, h2) do { int _s = (t) & 1; unsigned _k = (unsigned)(t) * 128u;             \
    __builtin_amdgcn_global_load_lds(                                                          \
        (__attribute__((address_space(1))) void*)(void*)(Bb + boff[h2][0] + _k),               \
        (__attribute__((address_space(3))) void*)&Bs[_s][((h2) * 1024 + wv * 64) * 8],         \
        16, 0, 0);                                                                             \
    __builtin_amdgcn_global_load_lds(                                                          \
        (__attribute__((address_space(1))) void*)(void*)(Bb + boff[h2][1] + _k),               \
        (__attribute__((address_space(3))) void*)&Bs[_s][((h2) * 1024 + 512 + wv * 64) * 8],   \
        16, 0, 0);                                                                             \
  } while (0)
#define RD_A(mi, kc) (*(const bf16x8*)&Ac[((((2 * (mi) + wr) * 16 + c) * 8 + (((kc) * 4 + g) ^ (c & 7))) * 8)])
#define RD_B(ni, kc) (*(const bf16x8*)&Bc[((((4 * (ni) + wc) * 16 + c) * 8 + (((kc) * 4 + g) ^ (c & 7))) * 8)])

  f32x4 acc[8][4];
#pragma unroll
  for (int mi = 0; mi < 8; ++mi)
#pragma unroll
    for (int ni = 0; ni < 4; ++ni)
      acc[mi][ni] = (f32x4){0.f, 0.f, 0.f, 0.f};

  STAGE_A(0, 0); STAGE_A(0, 1); STAGE_B(0, 0); STAGE_B(0, 1);
  STAGE_A(1, 0); STAGE_A(1, 1); STAGE_B(1, 0); STAGE_B(1, 1);
  asm volatile("s_waitcnt vmcnt(8)" ::: "memory");
  __builtin_amdgcn_s_barrier();

  bf16x8 af[4][2], bf[2][2];

#pragma unroll 1
  for (int v = 0; v < NT; ++v) {
    unsigned short* Ac = &As[v & 1][0];
    unsigned short* Bc = &Bs[v & 1][0];

    // ---- P1: quadrant (0,0)
#pragma unroll
    for (int i = 0; i < 4; ++i)
#pragma unroll
      for (int kc = 0; kc < 2; ++kc) af[i][kc] = RD_A(i, kc);
#pragma unroll
    for (int j = 0; j < 2; ++j)
#pragma unroll
      for (int kc = 0; kc < 2; ++kc) bf[j][kc] = RD_B(j, kc);
    if (v >= 1 && v + 1 < NT) STAGE_A(v + 1, 1);
    __builtin_amdgcn_s_barrier();
    asm volatile("s_waitcnt lgkmcnt(0)" ::: "memory");
    __builtin_amdgcn_sched_barrier(0);
    __builtin_amdgcn_s_setprio(1);
#pragma unroll
    for (int i = 0; i < 4; ++i)
#pragma unroll
      for (int j = 0; j < 2; ++j) {
        acc[i][j] = __builtin_amdgcn_mfma_f32_16x16x32_bf16(af[i][0], bf[j][0], acc[i][j], 0, 0, 0);
        acc[i][j] = __builtin_amdgcn_mfma_f32_16x16x32_bf16(af[i][1], bf[j][1], acc[i][j], 0, 0, 0);
      }
    __builtin_amdgcn_s_setprio(0);
    __builtin_amdgcn_s_barrier();

    // ---- P2: quadrant (0,1)
#pragma unroll
    for (int j = 0; j < 2; ++j)
#pragma unroll
      for (int kc = 0; kc < 2; ++kc) bf[j][kc] = RD_B(2 + j, kc);
    if (v >= 1 && v + 1 < NT) STAGE_B(v + 1, 0);
    __builtin_amdgcn_s_barrier();
    asm volatile("s_waitcnt lgkmcnt(0)" ::: "memory");
    __builtin_amdgcn_sched_barrier(0);
    __builtin_amdgcn_s_setprio(1);
#pragma unroll
    for (int i = 0; i < 4; ++i)
#pragma unroll
      for (int j = 0; j < 2; ++j) {
        acc[i][2 + j] = __builtin_amdgcn_mfma_f32_16x16x32_bf16(af[i][0], bf[j][0], acc[i][2 + j], 0, 0, 0);
        acc[i][2 + j] = __builtin_amdgcn_mfma_f32_16x16x32_bf16(af[i][1], bf[j][1], acc[i][2 + j], 0, 0, 0);
      }
    __builtin_amdgcn_s_setprio(0);
    __builtin_amdgcn_s_barrier();

    // ---- P3: quadrant (1,1)
#pragma unroll
    for (int i = 0; i < 4; ++i)
#pragma unroll
      for (int kc = 0; kc < 2; ++kc) af[i][kc] = RD_A(4 + i, kc);
    if (v + 2 < NT) STAGE_A(v + 2, 0);
    __builtin_amdgcn_s_barrier();
    asm volatile("s_waitcnt lgkmcnt(0)" ::: "memory");
    __builtin_amdgcn_sched_barrier(0);
    __builtin_amdgcn_s_setprio(1);
#pragma unroll
    for (int i = 0; i < 4; ++i)
#pragma unroll
      for (int j = 0; j < 2; ++j) {
        acc[4 + i][2 + j] = __builtin_amdgcn_mfma_f32_16x16x32_bf16(af[i][0], bf[j][0], acc[4 + i][2 + j], 0, 0, 0);
        acc[4 + i][2 + j] = __builtin_amdgcn_mfma_f32_16x16x32_bf16(af[i][1], bf[j][1], acc[4 + i][2 + j], 0, 0, 0);
      }
    __builtin_amdgcn_s_setprio(0);
    __builtin_amdgcn_s_barrier();

    // ---- P4: quadrant (1,0)
#pragma unroll
    for (int j = 0; j < 2; ++j)
#pragma unroll
      for (int kc = 0; kc < 2; ++kc) bf[j][kc] = RD_B(j, kc);
    if (v + 2 < NT) STAGE_B(v + 2, 1);
    __builtin_amdgcn_s_barrier();
    asm volatile("s_waitcnt lgkmcnt(0)" ::: "memory");
    __builtin_amdgcn_sched_barrier(0);
    __builtin_amdgcn_s_setprio(1);
#pragma unroll
    for (int i = 0; i < 4; ++i)
#pragma unroll
      for (int j = 0; j < 2; ++j) {
        acc[4 + i][j] = __builtin_amdgcn_mfma_f32_16x16x32_bf16(af[i][0], bf[j][0], acc[4 + i][j], 0, 0, 0);
        acc[4 + i][j] = __builtin_amdgcn_mfma_f32_16x16x32_bf16(af[i][1], bf[j][1], acc[4 + i][j], 0, 0, 0);
      }
    __builtin_amdgcn_s_setprio(0);
    if (v + 2 < NT) asm volatile("s_waitcnt vmcnt(4)" ::: "memory");
    else            asm volatile("s_waitcnt vmcnt(0)" ::: "memory");
    __builtin_amdgcn_s_barrier();
  }

#pragma unroll
  for (int ni = 0; ni < 4; ++ni) {
    int col = n0 + (4 * ni + wc) * 16 + c;
    float bv = bias[col];
#pragma unroll
    for (int mi = 0; mi < 8; ++mi) {
      int rowb = m0 + (2 * mi + wr) * 16 + g * 4;
#pragma unroll
      for (int rr = 0; rr < 4; ++rr) {
        float vv = acc[mi][ni][rr] + bv;
        if (OF32) ((float*)Cout)[(size_t)(rowb + rr) * Nn + col] = vv;
        else ((unsigned short*)Cout)[(size_t)(rowb + rr) * Nn + col] = f2bf(vv);
      }
    }
  }
#undef STAGE_A
#undef STAGE_B
#undef RD_A
#undef RD_B
}

// ---------------- attention: one workgroup per (p, h), 32x32 MFMA ----------
// m214-style: swapped QK^T (mfma(K,Q)) so lane l holds scores[q = q0+(l&31)]
// for 128 of 256 m (partner lane l^32 holds the rest). Softmax fully
// in-register (in-lane reduce + one shfl_xor(32)). P -> A-frag via
// v_cvt_pk_bf16_f32 + permlane32_swap (no P LDS round-trip).
// LDS = Ks 32K + Vt 32K = 64 KB -> 2 blocks/CU. No barriers in the t-loop.
// Layouts (verified against documented 32x32 C/D map:
//   col = lane&31, row = (reg&3) + 8*(reg>>2) + 4*(lane>>5)):
//   QK^T: A=K (lane: K[m=mt*32+lq][dk*16+hl*8+e]), B=Q^T (lane: Q[q0+lq][...])
//         -> sa[mt][r] = scores[q0+lq][mt*32 + (r&3)+8*(r>>2)+4*hl]
//   pack: L=regs rb..rb+3 (rows 4hl..), H=rb+4..rb+7 (rows 8+4hl..);
//         permlane32_swap(L,H) -> ret0 = frag k+{0,1}, ret1 = frag k+{4,5}
//   PV:   A=P, B=V (lane: V[kt*16+hl*8+e][dt*32+lq]) -> O: col=d, rows=q.
__global__ __launch_bounds__(256, 2) void attn_k(const unsigned short* __restrict__ qkv,
                                                 const int* __restrict__ order,
                                                 unsigned short* __restrict__ attnout) {
  __shared__ __align__(16) unsigned short Ks[KTOK * 64];   // [m][d], 16B-group XOR swizzle
  __shared__ __align__(16) unsigned short Vt[64 * 256];    // [d][m], XOR swizzle

  int p = blockIdx.x >> 3, h = blockIdx.x & 7;
  int tid = threadIdx.x;
  int wv = tid >> 6, ln = tid & 63;
  int lq = ln & 31;          // q-column (QK^T) / d-column (PV)
  int hl = ln >> 5;          // lane half

  const unsigned short* base = qkv + (size_t)p * KTOK * C3 + h * DHEAD;

  // --- K staging via global_load_lds DMA, swizzle via per-lane source addr --
  // Ks slot s (16B) holds K[m = s>>3][d-group (s&7) ^ (m&7)].
  {
    int mlo = tid >> 3;
    int j = (tid & 7) ^ (mlo & 7);               // i-independent per thread
    const unsigned short* ksrc = base + CDIM + j * 8;
#pragma unroll
    for (int i = 0; i < 8; ++i) {
      int m = i * 32 + mlo;
      __builtin_amdgcn_global_load_lds(
          (const __attribute__((address_space(1))) void*)(ksrc + (size_t)m * C3),
          (__attribute__((address_space(3))) void*)&Ks[((i << 8) + tid) * 8],
          16, 0, 0);
    }
  }
  // --- V staging: reg round-trip, transposed write (once per block) --------
  {
    const unsigned short* vrow = base + 2 * CDIM + (size_t)tid * C3;
    bf16x8 vv[8];
#pragma unroll
    for (int j = 0; j < 8; ++j) vv[j] = *(const bf16x8*)(vrow + j * 8);
#pragma unroll
    for (int j = 0; j < 8; ++j)
#pragma unroll
      for (int e = 0; e < 8; ++e) {
        int d = j * 8 + e;
        Vt[d * 256 + (((tid >> 3) ^ (d & 7)) << 3) + (tid & 7)] = (unsigned short)vv[j][e];
      }
  }

  // prefetch Q for t=0 (overlaps the staging drain)
  bf16x8 qfa[2][4];
  {
    const unsigned short* qr = base + (size_t)(wv * 64 + lq) * C3;
#pragma unroll
    for (int dk = 0; dk < 4; ++dk) qfa[0][dk] = *(const bf16x8*)(qr + dk * 16 + hl * 8);
  }
  __syncthreads();

#pragma unroll
  for (int t = 0; t < 2; ++t) {
    int q0 = wv * 64 + t * 32;
    int ordv[16];
#pragma unroll
    for (int r = 0; r < 16; ++r)
      ordv[r] = order[p * KTOK + q0 + (r & 3) + 8 * (r >> 2) + 4 * hl];

    // S^T = K Q^T : 8 m-tiles x 4 d-chunks
    f32x16 sa[8];
    __builtin_amdgcn_s_setprio(1);
#pragma unroll
    for (int mt = 0; mt < 8; ++mt) {
      f32x16 z;
#pragma unroll
      for (int r = 0; r < 16; ++r) z[r] = 0.f;
      int m = mt * 32 + lq;
#pragma unroll
      for (int dk = 0; dk < 4; ++dk) {
        bf16x8 kf = *(const bf16x8*)&Ks[(m * 8 + ((dk * 2 + hl) ^ (m & 7))) * 8];
        z = __builtin_amdgcn_mfma_f32_32x32x16_bf16(kf, qfa[t][dk], z, 0, 0, 0);
      }
      sa[mt] = z;
    }
    __builtin_amdgcn_s_setprio(0);

    // prefetch Q for t=1 (issues during softmax/PV of t=0)
    if (t == 0) {
      const unsigned short* qr = base + (size_t)(wv * 64 + 32 + lq) * C3;
#pragma unroll
      for (int dk = 0; dk < 4; ++dk) qfa[1][dk] = *(const bf16x8*)(qr + dk * 16 + hl * 8);
    }

    // softmax over m (lane: 128 values for q = q0+lq; partner has the rest)
    float mx = sa[0][0];
#pragma unroll
    for (int mt = 0; mt < 8; ++mt)
#pragma unroll
      for (int r = 0; r < 16; ++r) mx = fmaxf(mx, sa[mt][r]);
    mx = fmaxf(mx, __shfl_xor(mx, 32, 64));
    float sum = 0.f;
#pragma unroll
    for (int mt = 0; mt < 8; ++mt)
#pragma unroll
      for (int r = 0; r < 16; ++r) {
        float e = __expf((sa[mt][r] - mx) * 0.125f);
        sa[mt][r] = e;
        sum += e;
      }
    sum += __shfl_xor(sum, 32, 64);
    float inv = 1.f / sum;

    // O = P V : per 16-m chunk, pack A-frag in-register, 2 MFMAs (dt)
    f32x16 oa[2];
#pragma unroll
    for (int r = 0; r < 16; ++r) { oa[0][r] = 0.f; oa[1][r] = 0.f; }
#pragma unroll
    for (int kt = 0; kt < 16; ++kt) {
      int mt = kt >> 1, rb = (kt & 1) * 8;
      unsigned L0 = cvt_pk_bf16(sa[mt][rb + 0] * inv, sa[mt][rb + 1] * inv);
      unsigned L1 = cvt_pk_bf16(sa[mt][rb + 2] * inv, sa[mt][rb + 3] * inv);
      unsigned H0 = cvt_pk_bf16(sa[mt][rb + 4] * inv, sa[mt][rb + 5] * inv);
      unsigned H1 = cvt_pk_bf16(sa[mt][rb + 6] * inv, sa[mt][rb + 7] * inv);
      auto s0 = __builtin_amdgcn_permlane32_swap(L0, H0, false, false);
      auto s1 = __builtin_amdgcn_permlane32_swap(L1, H1, false, false);
      u32x4 pw;
      pw[0] = s0[0]; pw[1] = s1[0]; pw[2] = s0[1]; pw[3] = s1[1];
      bf16x8 pf = __builtin_bit_cast(bf16x8, pw);
      __builtin_amdgcn_s_setprio(1);
#pragma unroll
      for (int dt = 0; dt < 2; ++dt) {
        int d = dt * 32 + lq;
        bf16x8 vf = *(const bf16x8*)&Vt[(d * 32 + ((kt * 2 + hl) ^ (d & 7))) * 8];
        oa[dt] = __builtin_amdgcn_mfma_f32_32x32x16_bf16(pf, vf, oa[dt], 0, 0, 0);
      }
      __builtin_amdgcn_s_setprio(0);
    }

    // scatter store: row = order[q], cols h*64 + {lq, lq+32} (64B segments)
    size_t cb = (size_t)h * DHEAD + lq;
#pragma unroll
    for (int r = 0; r < 16; ++r) {
      size_t rb2 = (size_t)ordv[r] * CDIM + cb;
      attnout[rb2] = f2bf(oa[0][r]);
      attnout[rb2 + 32] = f2bf(oa[1][r]);
    }
  }
}

extern "C" void kernel_launch(void* const* d_in, const int* in_sizes, int n_in,
                              void* d_out, int out_size, void* d_ws, size_t ws_size,
                              hipStream_t stream) {
  const float* feat  = (const float*)d_in[0];
  const int*   order = (const int*)d_in[1];
  // d_in[2] = inverse (unused: we scatter by order instead)
  const float* Wqkv  = (const float*)d_in[3];
  const float* bqkv  = (const float*)d_in[4];
  const float* Wproj = (const float*)d_in[5];
  const float* bproj = (const float*)d_in[6];
  float* out = (float*)d_out;

  char* ws = (char*)d_ws;
  unsigned short* qkv    = (unsigned short*)ws;
  unsigned short* featb  = (unsigned short*)(ws + (size_t)N_TOK * C3 * 2);
  unsigned short* attn   = featb;  // disjoint lifetime
  unsigned short* wqkvT  = (unsigned short*)(ws + (size_t)N_TOK * C3 * 2 + (size_t)N_TOK * CDIM * 2);
  unsigned short* wprojT = wqkvT + C3 * CDIM;

  cvt_f32_bf16<<<(N_TOK * CDIM) / (256 * 4), 256, 0, stream>>>(feat, featb);
  transpose_cvt<<<dim3(C3 / 32, CDIM / 32), 256, 0, stream>>>(Wqkv, wqkvT, CDIM, C3);
  transpose_cvt<<<dim3(CDIM / 32, CDIM / 32), 256, 0, stream>>>(Wproj, wprojT, CDIM, CDIM);

  gemm256<0><<<(N_TOK / 256) * (C3 / 256), 512, 0, stream>>>(
      featb, wqkvT, bqkv, qkv, order, C3, CDIM, C3 / 256);

  attn_k<<<PGRP * HEADS, 256, 0, stream>>>(qkv, order, attn);

  gemm256<1><<<(N_TOK / 256) * (CDIM / 256), 512, 0, stream>>>(
      attn, wprojT, bproj, out, nullptr, CDIM, CDIM, CDIM / 256);
}